// Round 1
// 602.739 us; speedup vs baseline: 1.0982x; 1.0982x over previous
//
#include <hip/hip_runtime.h>

#define N_ROWS 100000
#define KNB 16
#define XN 128
#define XE 64
#define XO 128
#define AP 328             // padded A-row in bf16 elems (656B row -> ~2-way LDS aliasing)
#define MT 32              // rows per tile; 100000 % 32 == 0
#define NTILES (N_ROWS / MT)   // 3125 blocks, exactly 1 tile each
#define TPB 512

typedef __attribute__((ext_vector_type(8))) short bf16x8_t;   // 8 bf16 = 4 VGPRs
typedef __attribute__((ext_vector_type(4))) float f32x4_t;

__device__ __forceinline__ short f2bf(float f) {
  union { float f; unsigned u; } v; v.f = f;
  unsigned r = v.u + 0x7fffu + ((v.u >> 16) & 1u);   // RNE; inputs finite
  return (short)(r >> 16);
}
__device__ __forceinline__ float bf2f(short s) {
  union { unsigned u; float f; } v;
  v.u = ((unsigned)(unsigned short)s) << 16;
  return v.f;
}

// ij is int64 in the reference; harness may hand us int32. int64 little-endian:
// odd 32-bit words are hi-words of small nonneg indices -> all 0.
__global__ void detect_idx_kernel(const int* __restrict__ ij32, int* __restrict__ flag) {
  if (threadIdx.x == 0 && blockIdx.x == 0) {
    int all0 = 1;
    for (int i = 0; i < 16; ++i) all0 &= (ij32[2 * i + 1] == 0) ? 1 : 0;
    *flag = all0;   // 1 => int64 layout, 0 => int32 layout
  }
}

// ---- pre-pass: cast x and Wc/Wn/We to bf16 in workspace -----------------
#define XCH  (N_ROWS * XN / 8)   // 1,600,000 chunks of 8 floats
#define WCCH (XO * XN / 8)       // 2048
#define WECH (XO * XE / 8)       // 1024
__global__ __launch_bounds__(256) void cast_kernel(
    const float* __restrict__ x, const float* __restrict__ Wc,
    const float* __restrict__ Wn, const float* __restrict__ We,
    short* __restrict__ xb, short* __restrict__ wb) {
  const int total = XCH + 2 * WCCH + WECH;
  for (int i = blockIdx.x * blockDim.x + threadIdx.x; i < total;
       i += gridDim.x * blockDim.x) {
    const float* s; short* d;
    if (i < XCH) { s = x + (size_t)i * 8; d = xb + (size_t)i * 8; }
    else {
      int j = i - XCH;
      if (j < WCCH)          { s = Wc + j * 8;              d = wb + j * 8; }
      else if (j < 2 * WCCH) { s = Wn + (j - WCCH) * 8;     d = wb + XO * XN + (j - WCCH) * 8; }
      else                   { s = We + (j - 2 * WCCH) * 8; d = wb + 2 * XO * XN + (j - 2 * WCCH) * 8; }
    }
    f32x4_t a = __builtin_nontemporal_load((const f32x4_t*)s);
    f32x4_t b = __builtin_nontemporal_load((const f32x4_t*)s + 1);
    bf16x8_t r;
    r[0] = f2bf(a[0]); r[1] = f2bf(a[1]); r[2] = f2bf(a[2]); r[3] = f2bf(a[3]);
    r[4] = f2bf(b[0]); r[5] = f2bf(b[1]); r[6] = f2bf(b[2]); r[7] = f2bf(b[3]);
    *(bf16x8_t*)d = r;   // cacheable store: this is the gather working set
  }
}

// ---- main kernel: one 32-row tile per 512-thread block, 1 barrier -------
template<bool XB>
__global__ __launch_bounds__(TPB, 4) void conv_fused_kernel(
    const float* __restrict__ x, const short* __restrict__ xb,
    const float* __restrict__ e, const int* __restrict__ ij32,
    const float* __restrict__ Wc, const float* __restrict__ Wn,
    const float* __restrict__ We, const short* __restrict__ wb,
    const int* __restrict__ flag, float* __restrict__ out)
{
  __shared__ __align__(16) short As[MT][AP];   // [x | xnj | xej] as bf16

  const int tid  = threadIdx.x;
  const int wave = tid >> 6;       // 0..7
  const int lane = tid & 63;
  const int quad = lane >> 4;
  const int l16  = lane & 15;
  const int r    = tid >> 4;       // row within tile (0..31)
  const int s16  = tid & 15;       // column-group within row

  const int shift = (*flag) ? 2 : 1;
  const int r0 = blockIdx.x * MT;

  // gather index for (row r, slot s16) — owner lanes of a row are in the same wave
  int myidx = __builtin_nontemporal_load(ij32 + (((r0 + r) * KNB + s16) << shift));
  myidx = myidx < 0 ? 0 : (myidx >= N_ROWS ? N_ROWS - 1 : myidx);   // safety clamp

  // ---- x row -> As[:, 0:128]
  if constexpr (XB) {
    *(bf16x8_t*)(&As[r][s16 * 8]) = *(const bf16x8_t*)(xb + (r0 + r) * XN + s16 * 8);
  } else {
    const float* p = x + (r0 + r) * XN + s16 * 8;
    f32x4_t a = *(const f32x4_t*)p;
    f32x4_t b = *(const f32x4_t*)(p + 4);
    short* dst = &As[r][s16 * 8];
    dst[0] = f2bf(a[0]); dst[1] = f2bf(a[1]); dst[2] = f2bf(a[2]); dst[3] = f2bf(a[3]);
    dst[4] = f2bf(b[0]); dst[5] = f2bf(b[1]); dst[6] = f2bf(b[2]); dst[7] = f2bf(b[3]);
  }

  // ---- gather mean -> As[:, 128:256]  (8 cols of one row per thread)
  {
    float s0=0,s1=0,s2=0,s3=0,s4=0,s5=0,s6=0,s7=0;
    #pragma unroll
    for (int k = 0; k < KNB; ++k) {
      const int idx = __shfl(myidx, (lane & 48) | k, 64);  // idx(row r, k), same wave
      if constexpr (XB) {
        bf16x8_t v = *(const bf16x8_t*)(xb + idx * XN + s16 * 8);
        s0 += bf2f(v[0]); s1 += bf2f(v[1]); s2 += bf2f(v[2]); s3 += bf2f(v[3]);
        s4 += bf2f(v[4]); s5 += bf2f(v[5]); s6 += bf2f(v[6]); s7 += bf2f(v[7]);
      } else {
        const float* p = x + idx * XN + s16 * 8;
        f32x4_t a = *(const f32x4_t*)p;
        f32x4_t b = *(const f32x4_t*)(p + 4);
        s0 += a[0]; s1 += a[1]; s2 += a[2]; s3 += a[3];
        s4 += b[0]; s5 += b[1]; s6 += b[2]; s7 += b[3];
      }
    }
    short* dst = &As[r][128 + s16 * 8];
    dst[0] = f2bf(s0 * 0.0625f); dst[1] = f2bf(s1 * 0.0625f);
    dst[2] = f2bf(s2 * 0.0625f); dst[3] = f2bf(s3 * 0.0625f);
    dst[4] = f2bf(s4 * 0.0625f); dst[5] = f2bf(s5 * 0.0625f);
    dst[6] = f2bf(s6 * 0.0625f); dst[7] = f2bf(s7 * 0.0625f);
  }

  // ---- e mean -> As[:, 256:320]  (4 cols of one row per thread; nt stream)
  {
    const float* p = e + (size_t)(r0 + r) * (KNB * XE) + s16 * 4;
    float sx = 0.f, sy = 0.f, sz = 0.f, sw = 0.f;
    #pragma unroll
    for (int k = 0; k < KNB; ++k) {
      f32x4_t v = __builtin_nontemporal_load((const f32x4_t*)(p + k * XE));
      sx += v[0]; sy += v[1]; sz += v[2]; sw += v[3];
    }
    short* dst = &As[r][256 + s16 * 4];
    dst[0] = f2bf(sx * 0.0625f); dst[1] = f2bf(sy * 0.0625f);
    dst[2] = f2bf(sz * 0.0625f); dst[3] = f2bf(sw * 0.0625f);
  }

  // ---- B fragments: wave owns output cols [16*wave, 16*wave+16)
  // B[k][j] = W_all[j][k]; lane holds (k = ks*32 + quad*8 + 0..7, j = 16*wave + l16)
  bf16x8_t bfrag[10];
  const int col = wave * 16 + l16;
  #pragma unroll
  for (int ks = 0; ks < 10; ++ks) {
    const int k = ks * 32 + quad * 8;     // never crosses the 128/256 boundaries
    if constexpr (XB) {
      const short* src;
      if (k < 128)      src = wb + col * XN + k;
      else if (k < 256) src = wb + XO * XN + col * XN + (k - 128);
      else              src = wb + 2 * XO * XN + col * XE + (k - 256);
      bfrag[ks] = *(const bf16x8_t*)src;
    } else {
      const float* src;
      if (k < 128)      src = Wc + col * XN + k;
      else if (k < 256) src = Wn + col * XN + (k - 128);
      else              src = We + col * XE + (k - 256);
      f32x4_t a = *(const f32x4_t*)src;
      f32x4_t b = *(const f32x4_t*)(src + 4);
      bf16x8_t f;
      f[0] = f2bf(a[0]); f[1] = f2bf(a[1]); f[2] = f2bf(a[2]); f[3] = f2bf(a[3]);
      f[4] = f2bf(b[0]); f[5] = f2bf(b[1]); f[6] = f2bf(b[2]); f[7] = f2bf(b[3]);
      bfrag[ks] = f;
    }
  }

  __syncthreads();   // the only barrier: A-tile complete

  // ---- MFMA: 2 row-halves x 16 cols per wave, K=320 in 10 steps
  f32x4_t acc0 = {0.f, 0.f, 0.f, 0.f};
  f32x4_t acc1 = {0.f, 0.f, 0.f, 0.f};
  #pragma unroll
  for (int ks = 0; ks < 10; ++ks) {
    bf16x8_t a0 = *(const bf16x8_t*)(&As[l16][ks * 32 + quad * 8]);
    bf16x8_t a1 = *(const bf16x8_t*)(&As[l16 + 16][ks * 32 + quad * 8]);
    acc0 = __builtin_amdgcn_mfma_f32_16x16x32_bf16(a0, bfrag[ks], acc0, 0, 0, 0);
    acc1 = __builtin_amdgcn_mfma_f32_16x16x32_bf16(a1, bfrag[ks], acc1, 0, 0, 0);
  }

  // epilogue: C/D layout col = lane&15, row = quad*4 + reg; nt stores
  #pragma unroll
  for (int i = 0; i < 4; ++i) {
    const int row0 = r0 + quad * 4 + i;
    __builtin_nontemporal_store(fmaxf(acc0[i], 0.f), out + row0 * XO + col);
    __builtin_nontemporal_store(fmaxf(acc1[i], 0.f), out + (row0 + 16) * XO + col);
  }
}

extern "C" void kernel_launch(void* const* d_in, const int* in_sizes, int n_in,
                              void* d_out, int out_size, void* d_ws, size_t ws_size,
                              hipStream_t stream) {
  const float* x  = (const float*)d_in[0];
  const float* e  = (const float*)d_in[1];
  const int* ij32 = (const int*)d_in[2];
  const float* Wc = (const float*)d_in[3];
  const float* Wn = (const float*)d_in[4];
  const float* We = (const float*)d_in[5];
  float* out = (float*)d_out;

  int* flag = (int*)d_ws;
  const size_t xb_off   = 256;
  const size_t xb_elems = (size_t)N_ROWS * XN;
  const size_t wb_elems = (size_t)(2 * XO * XN + XO * XE);
  const size_t need     = xb_off + (xb_elems + wb_elems) * sizeof(short);

  detect_idx_kernel<<<1, 64, 0, stream>>>(ij32, flag);
  if (ws_size >= need) {
    short* xb = (short*)((char*)d_ws + xb_off);
    short* wb = xb + xb_elems;
    cast_kernel<<<2048, 256, 0, stream>>>(x, Wc, Wn, We, xb, wb);
    conv_fused_kernel<true><<<NTILES, TPB, 0, stream>>>(
        x, xb, e, ij32, Wc, Wn, We, wb, flag, out);
  } else {
    conv_fused_kernel<false><<<NTILES, TPB, 0, stream>>>(
        x, nullptr, e, ij32, Wc, Wn, We, nullptr, flag, out);
  }
}